// Round 3
// baseline (44.881 us; speedup 1.0000x reference)
//
#include <hip/hip_runtime.h>
#include <math.h>

#define EPS_REG 1e-6f
#define MIN_EIG_F 1e-4f
#define RB 8        // rows per block in fused beta pass

// ---------- 3x3 helpers ----------

__device__ __forceinline__ void sym_inv3(const float m[3][3], float o[3][3]) {
    float c00 = m[1][1]*m[2][2] - m[1][2]*m[2][1];
    float c01 = m[1][2]*m[2][0] - m[1][0]*m[2][2];
    float c02 = m[1][0]*m[2][1] - m[1][1]*m[2][0];
    float det = m[0][0]*c00 + m[0][1]*c01 + m[0][2]*c02;
    float inv = 1.0f / det;
    o[0][0] = c00*inv;
    o[1][0] = c01*inv;
    o[2][0] = c02*inv;
    o[0][1] = (m[0][2]*m[2][1]-m[0][1]*m[2][2])*inv;
    o[1][1] = (m[0][0]*m[2][2]-m[0][2]*m[2][0])*inv;
    o[2][1] = (m[0][1]*m[2][0]-m[0][0]*m[2][1])*inv;
    o[0][2] = (m[0][1]*m[1][2]-m[0][2]*m[1][1])*inv;
    o[1][2] = (m[0][2]*m[1][0]-m[0][0]*m[1][2])*inv;
    o[2][2] = (m[0][0]*m[1][1]-m[0][1]*m[1][0])*inv;
}

__device__ __forceinline__ void jrot(float A[3][3], float V[3][3], int p, int q) {
    float apq = A[p][q];
    if (fabsf(apq) < 1e-20f) return;
    float theta = (A[q][q] - A[p][p]) / (2.0f * apq);
    float t = 1.0f / (fabsf(theta) + sqrtf(1.0f + theta*theta));
    if (theta < 0.0f) t = -t;
    float c = 1.0f / sqrtf(1.0f + t*t);
    float s = t * c;
    int r = 3 - p - q;
    float apq_t = t*apq;
    A[p][p] -= apq_t;
    A[q][q] += apq_t;
    A[p][q] = 0.0f; A[q][p] = 0.0f;
    float arp = A[r][p], arq = A[r][q];
    A[r][p] = c*arp - s*arq; A[p][r] = A[r][p];
    A[r][q] = s*arp + c*arq; A[q][r] = A[r][q];
    #pragma unroll
    for (int k = 0; k < 3; k++) {
        float vkp = V[k][p], vkq = V[k][q];
        V[k][p] = c*vkp - s*vkq;
        V[k][q] = s*vkp + c*vkq;
    }
}

// ---------- kernel A: per-point precompute ----------
__global__ void precompute_kernel(const float* __restrict__ Sp,
                                  const float* __restrict__ Sq,
                                  const float* __restrict__ phi,
                                  float* __restrict__ Lp,
                                  float* __restrict__ Lq,
                                  float* __restrict__ Rm,
                                  float* __restrict__ S,
                                  int BN) {
    int t = blockIdx.x * blockDim.x + threadIdx.x;
    if (t >= BN) return;

    float m[3][3], lq[3][3], lp[3][3];
    const float* p = Sq + (size_t)t * 9;
    #pragma unroll
    for (int i = 0; i < 3; i++)
        #pragma unroll
        for (int j = 0; j < 3; j++) m[i][j] = p[i*3 + j];
    m[0][0] += EPS_REG; m[1][1] += EPS_REG; m[2][2] += EPS_REG;
    sym_inv3(m, lq);

    p = Sp + (size_t)t * 9;
    #pragma unroll
    for (int i = 0; i < 3; i++)
        #pragma unroll
        for (int j = 0; j < 3; j++) m[i][j] = p[i*3 + j];
    m[0][0] += EPS_REG; m[1][1] += EPS_REG; m[2][2] += EPS_REG;
    sym_inv3(m, lp);

    float* o = Lq + (size_t)t * 6;
    o[0]=lq[0][0]; o[1]=lq[0][1]; o[2]=lq[0][2]; o[3]=lq[1][1]; o[4]=lq[1][2]; o[5]=lq[2][2];
    o = Lp + (size_t)t * 6;
    o[0]=lp[0][0]; o[1]=lp[0][1]; o[2]=lp[0][2]; o[3]=lp[1][1]; o[4]=lp[1][2]; o[5]=lp[2][2];

    // Rodrigues: R = I + a*K + b*K^2, exact expm for skew input
    float w0 = phi[(size_t)t*3], w1 = phi[(size_t)t*3+1], w2 = phi[(size_t)t*3+2];
    float th2 = w0*w0 + w1*w1 + w2*w2;
    float th = sqrtf(th2);
    float a, b;
    if (th < 1e-4f) { a = 1.0f - th2*(1.0f/6.0f); b = 0.5f - th2*(1.0f/24.0f); }
    else            { a = sinf(th)/th;            b = (1.0f - cosf(th))/th2; }
    float R[3][3];
    R[0][0] = 1.0f + b*(w0*w0 - th2); R[0][1] = -a*w2 + b*w0*w1;        R[0][2] =  a*w1 + b*w0*w2;
    R[1][0] =  a*w2 + b*w0*w1;        R[1][1] = 1.0f + b*(w1*w1 - th2); R[1][2] = -a*w0 + b*w1*w2;
    R[2][0] = -a*w1 + b*w0*w2;        R[2][1] =  a*w0 + b*w1*w2;        R[2][2] = 1.0f + b*(w2*w2 - th2);
    o = Rm + (size_t)t * 9;
    #pragma unroll
    for (int i = 0; i < 3; i++)
        #pragma unroll
        for (int j = 0; j < 3; j++) o[i*3 + j] = R[i][j];

    // S = R^T * Lq * R
    float U[3][3], Sv[3][3];
    #pragma unroll
    for (int i = 0; i < 3; i++)
        #pragma unroll
        for (int j = 0; j < 3; j++)
            U[i][j] = lq[i][0]*R[0][j] + lq[i][1]*R[1][j] + lq[i][2]*R[2][j];
    #pragma unroll
    for (int i = 0; i < 3; i++)
        #pragma unroll
        for (int j = 0; j < 3; j++)
            Sv[i][j] = R[0][i]*U[0][j] + R[1][i]*U[1][j] + R[2][i]*U[2][j];
    o = S + (size_t)t * 6;
    o[0]=Sv[0][0]; o[1]=Sv[0][1]; o[2]=Sv[0][2]; o[3]=Sv[1][1]; o[4]=Sv[1][2]; o[5]=Sv[2][2];
}

// ---------- kernel B (fused): one pass over beta ----------
// Block: 256 threads, RB=8 rows. Thread owns 4 consecutive cols per j-tile
// (j-tile = 1024 cols). Computes:
//   T[row]   = sum_j beta[row][j] * S[j]     (register-tiled, shuffle-reduced)
//   partial[b][chunk][col] = sum_{r in chunk} beta[r][col]   (free from regs)
__global__ __launch_bounds__(256) void fused_beta_kernel(
        const float* __restrict__ beta,
        const float* __restrict__ S,
        float* __restrict__ T,
        float* __restrict__ partial,  // B * (N/RB) * N
        int B, int N) {
    int tid = threadIdx.x;
    int grow0 = blockIdx.x * RB;         // global row start (B*N space)
    int b = grow0 / N;
    int chunksPerB = N / RB;
    int chunk = (grow0 - b * N) / RB;
    const float* sb = S + (size_t)b * N * 6;

    float acc[RB][6];
    #pragma unroll
    for (int r = 0; r < RB; r++)
        #pragma unroll
        for (int c = 0; c < 6; c++) acc[r][c] = 0.0f;

    int jtiles = N / 1024;               // 4 cols/thread * 256 threads
    for (int jt = 0; jt < jtiles; jt++) {
        int c0 = jt * 1024 + 4 * tid;
        // S for 4 consecutive cols = 24 contiguous floats
        float4 s4[6];
        const float4* sp = (const float4*)(sb + (size_t)c0 * 6);
        #pragma unroll
        for (int u = 0; u < 6; u++) s4[u] = sp[u];
        const float* sv = (const float*)s4;   // sv[u*6 + c] = S[c0+u][c]

        float csum0 = 0.f, csum1 = 0.f, csum2 = 0.f, csum3 = 0.f;
        #pragma unroll
        for (int r = 0; r < RB; r++) {
            float4 w4 = *(const float4*)(beta + (size_t)(grow0 + r) * N + c0);
            csum0 += w4.x; csum1 += w4.y; csum2 += w4.z; csum3 += w4.w;
            #pragma unroll
            for (int c = 0; c < 6; c++) {
                acc[r][c] += w4.x * sv[0*6 + c];
                acc[r][c] += w4.y * sv[1*6 + c];
                acc[r][c] += w4.z * sv[2*6 + c];
                acc[r][c] += w4.w * sv[3*6 + c];
            }
        }
        *(float4*)(partial + ((size_t)b * chunksPerB + chunk) * N + c0) =
            make_float4(csum0, csum1, csum2, csum3);
    }

    // reduce acc[r][c] over 256 threads -> T
    __shared__ float red[4][RB * 6];
    int wid = tid >> 6, lane = tid & 63;
    #pragma unroll
    for (int r = 0; r < RB; r++)
        #pragma unroll
        for (int c = 0; c < 6; c++) {
            float v = acc[r][c];
            #pragma unroll
            for (int off = 32; off > 0; off >>= 1) v += __shfl_xor(v, off);
            if (lane == 0) red[wid][r * 6 + c] = v;
        }
    __syncthreads();
    if (tid < RB * 6) {
        float v = red[0][tid] + red[1][tid] + red[2][tid] + red[3][tid];
        T[(size_t)grow0 * 6 + tid] = v;   // 48 contiguous floats
    }
}

// ---------- kernel D: finalize ----------
__global__ void finalize_kernel(const float* __restrict__ Lp,
                                const float* __restrict__ Lq,
                                const float* __restrict__ Rm,
                                const float* __restrict__ T,
                                const float* __restrict__ partial,
                                float* __restrict__ out,
                                int B, int N) {
    int t = blockIdx.x * blockDim.x + threadIdx.x;
    int BN = B * N;
    if (t >= BN) return;
    int b = t / N;
    int i = t - b * N;

    int chunksPerB = N / RB;
    float cs = 0.0f;
    #pragma unroll 8
    for (int c = 0; c < chunksPerB; c++)
        cs += partial[((size_t)b * chunksPerB + c) * N + i];

    const float* p = Rm + (size_t)t * 9;
    float R[3][3];
    #pragma unroll
    for (int ii = 0; ii < 3; ii++)
        #pragma unroll
        for (int jj = 0; jj < 3; jj++) R[ii][jj] = p[ii*3 + jj];

    const float* tp = T + (size_t)t * 6;
    float Tm[3][3] = {{tp[0],tp[1],tp[2]},{tp[1],tp[3],tp[4]},{tp[2],tp[4],tp[5]}};
    const float* lpp = Lp + (size_t)t * 6;
    const float* lqp = Lq + (size_t)t * 6;
    float Lpf[3][3] = {{lpp[0],lpp[1],lpp[2]},{lpp[1],lpp[3],lpp[4]},{lpp[2],lpp[4],lpp[5]}};
    float Lqf[3][3] = {{lqp[0],lqp[1],lqp[2]},{lqp[1],lqp[3],lqp[4]},{lqp[2],lqp[4],lqp[5]}};

    // M = Lp + R*Tm*R^T + cs*Lq
    float U[3][3], M[3][3];
    #pragma unroll
    for (int ii = 0; ii < 3; ii++)
        #pragma unroll
        for (int jj = 0; jj < 3; jj++)
            U[ii][jj] = R[ii][0]*Tm[0][jj] + R[ii][1]*Tm[1][jj] + R[ii][2]*Tm[2][jj];
    #pragma unroll
    for (int ii = 0; ii < 3; ii++)
        #pragma unroll
        for (int jj = 0; jj < 3; jj++) {
            float min_ij = U[ii][0]*R[jj][0] + U[ii][1]*R[jj][1] + U[ii][2]*R[jj][2];
            M[ii][jj] = Lpf[ii][jj] + min_ij + cs * Lqf[ii][jj];
        }
    // symmetrize
    float A[3][3];
    #pragma unroll
    for (int ii = 0; ii < 3; ii++)
        #pragma unroll
        for (int jj = 0; jj < 3; jj++) A[ii][jj] = 0.5f * (M[ii][jj] + M[jj][ii]);

    // Jacobi eigensolve, 6 sweeps
    float V[3][3] = {{1,0,0},{0,1,0},{0,0,1}};
    #pragma unroll
    for (int sweep = 0; sweep < 6; sweep++) {
        jrot(A, V, 0, 1);
        jrot(A, V, 0, 2);
        jrot(A, V, 1, 2);
    }
    float w0 = fmaxf(A[0][0], MIN_EIG_F);
    float w1 = fmaxf(A[1][1], MIN_EIG_F);
    float w2 = fmaxf(A[2][2], MIN_EIG_F);
    float iw0 = 1.0f/w0, iw1 = 1.0f/w1, iw2 = 1.0f/w2;

    float* opd = out + (size_t)t * 9;
    float* oin = out + (size_t)BN * 9 + (size_t)t * 9;
    #pragma unroll
    for (int ii = 0; ii < 3; ii++)
        #pragma unroll
        for (int jj = 0; jj < 3; jj++) {
            float pd = V[ii][0]*w0*V[jj][0] + V[ii][1]*w1*V[jj][1] + V[ii][2]*w2*V[jj][2];
            float iv = V[ii][0]*iw0*V[jj][0] + V[ii][1]*iw1*V[jj][1] + V[ii][2]*iw2*V[jj][2];
            opd[ii*3 + jj] = pd;
            oin[ii*3 + jj] = iv;
        }
}

extern "C" void kernel_launch(void* const* d_in, const int* in_sizes, int n_in,
                              void* d_out, int out_size, void* d_ws, size_t ws_size,
                              hipStream_t stream) {
    const float* Sp   = (const float*)d_in[0];
    const float* Sq   = (const float*)d_in[1];
    const float* phi  = (const float*)d_in[2];
    const float* beta = (const float*)d_in[3];

    int BN = in_sizes[2] / 3;                 // B*N
    int N  = (int)((long long)in_sizes[3] / BN);
    int B  = BN / N;

    float* ws = (float*)d_ws;
    float* Lp = ws;                   // BN*6
    float* Lq = Lp + (size_t)BN * 6;  // BN*6
    float* Rm = Lq + (size_t)BN * 6;  // BN*9
    float* S  = Rm + (size_t)BN * 9;  // BN*6
    float* T  = S  + (size_t)BN * 6;  // BN*6
    float* partial = T + (size_t)BN * 6; // B*(N/RB)*N

    float* outf = (float*)d_out;

    precompute_kernel<<<(BN + 63)/64, 64, 0, stream>>>(Sp, Sq, phi, Lp, Lq, Rm, S, BN);

    // fused beta pass: one block per RB rows
    fused_beta_kernel<<<BN / RB, 256, 0, stream>>>(beta, S, T, partial, B, N);

    finalize_kernel<<<(BN + 63)/64, 64, 0, stream>>>(Lp, Lq, Rm, T, partial, outf, B, N);
}

// Round 4
// 26.845 us; speedup vs baseline: 1.6718x; 1.6718x over previous
//
#include <hip/hip_runtime.h>
#include <math.h>

#define EPS_REG 1e-6f
#define MIN_EIG_F 1e-4f
#define RB 8        // rows per block in fused beta pass
#define NCH2 32     // chunks after hop reduction

// ---------- 3x3 helpers ----------

__device__ __forceinline__ void sym_inv3(const float m[3][3], float o[3][3]) {
    float c00 = m[1][1]*m[2][2] - m[1][2]*m[2][1];
    float c01 = m[1][2]*m[2][0] - m[1][0]*m[2][2];
    float c02 = m[1][0]*m[2][1] - m[1][1]*m[2][0];
    float det = m[0][0]*c00 + m[0][1]*c01 + m[0][2]*c02;
    float inv = 1.0f / det;
    o[0][0] = c00*inv;
    o[1][0] = c01*inv;
    o[2][0] = c02*inv;
    o[0][1] = (m[0][2]*m[2][1]-m[0][1]*m[2][2])*inv;
    o[1][1] = (m[0][0]*m[2][2]-m[0][2]*m[2][0])*inv;
    o[2][1] = (m[0][1]*m[2][0]-m[0][0]*m[2][1])*inv;
    o[0][2] = (m[0][1]*m[1][2]-m[0][2]*m[1][1])*inv;
    o[1][2] = (m[0][2]*m[1][0]-m[0][0]*m[1][2])*inv;
    o[2][2] = (m[0][0]*m[1][1]-m[0][1]*m[1][0])*inv;
}

__device__ __forceinline__ void jrot(float A[3][3], float V[3][3], int p, int q) {
    float apq = A[p][q];
    if (fabsf(apq) < 1e-20f) return;
    float theta = (A[q][q] - A[p][p]) / (2.0f * apq);
    float t = 1.0f / (fabsf(theta) + sqrtf(1.0f + theta*theta));
    if (theta < 0.0f) t = -t;
    float c = 1.0f / sqrtf(1.0f + t*t);
    float s = t * c;
    int r = 3 - p - q;
    float apq_t = t*apq;
    A[p][p] -= apq_t;
    A[q][q] += apq_t;
    A[p][q] = 0.0f; A[q][p] = 0.0f;
    float arp = A[r][p], arq = A[r][q];
    A[r][p] = c*arp - s*arq; A[p][r] = A[r][p];
    A[r][q] = s*arp + c*arq; A[q][r] = A[r][q];
    #pragma unroll
    for (int k = 0; k < 3; k++) {
        float vkp = V[k][p], vkq = V[k][q];
        V[k][p] = c*vkp - s*vkq;
        V[k][q] = s*vkp + c*vkq;
    }
}

// ---------- kernel A: per-point precompute ----------
__global__ void precompute_kernel(const float* __restrict__ Sp,
                                  const float* __restrict__ Sq,
                                  const float* __restrict__ phi,
                                  float* __restrict__ Lp,
                                  float* __restrict__ Lq,
                                  float* __restrict__ Rm,
                                  float* __restrict__ S,
                                  int BN) {
    int t = blockIdx.x * blockDim.x + threadIdx.x;
    if (t >= BN) return;

    float m[3][3], lq[3][3], lp[3][3];
    const float* p = Sq + (size_t)t * 9;
    #pragma unroll
    for (int i = 0; i < 3; i++)
        #pragma unroll
        for (int j = 0; j < 3; j++) m[i][j] = p[i*3 + j];
    m[0][0] += EPS_REG; m[1][1] += EPS_REG; m[2][2] += EPS_REG;
    sym_inv3(m, lq);

    p = Sp + (size_t)t * 9;
    #pragma unroll
    for (int i = 0; i < 3; i++)
        #pragma unroll
        for (int j = 0; j < 3; j++) m[i][j] = p[i*3 + j];
    m[0][0] += EPS_REG; m[1][1] += EPS_REG; m[2][2] += EPS_REG;
    sym_inv3(m, lp);

    float* o = Lq + (size_t)t * 6;
    o[0]=lq[0][0]; o[1]=lq[0][1]; o[2]=lq[0][2]; o[3]=lq[1][1]; o[4]=lq[1][2]; o[5]=lq[2][2];
    o = Lp + (size_t)t * 6;
    o[0]=lp[0][0]; o[1]=lp[0][1]; o[2]=lp[0][2]; o[3]=lp[1][1]; o[4]=lp[1][2]; o[5]=lp[2][2];

    // Rodrigues: R = I + a*K + b*K^2, exact expm for skew input
    float w0 = phi[(size_t)t*3], w1 = phi[(size_t)t*3+1], w2 = phi[(size_t)t*3+2];
    float th2 = w0*w0 + w1*w1 + w2*w2;
    float th = sqrtf(th2);
    float a, b;
    if (th < 1e-4f) { a = 1.0f - th2*(1.0f/6.0f); b = 0.5f - th2*(1.0f/24.0f); }
    else            { a = sinf(th)/th;            b = (1.0f - cosf(th))/th2; }
    float R[3][3];
    R[0][0] = 1.0f + b*(w0*w0 - th2); R[0][1] = -a*w2 + b*w0*w1;        R[0][2] =  a*w1 + b*w0*w2;
    R[1][0] =  a*w2 + b*w0*w1;        R[1][1] = 1.0f + b*(w1*w1 - th2); R[1][2] = -a*w0 + b*w1*w2;
    R[2][0] = -a*w1 + b*w0*w2;        R[2][1] =  a*w0 + b*w1*w2;        R[2][2] = 1.0f + b*(w2*w2 - th2);
    o = Rm + (size_t)t * 9;
    #pragma unroll
    for (int i = 0; i < 3; i++)
        #pragma unroll
        for (int j = 0; j < 3; j++) o[i*3 + j] = R[i][j];

    // S = R^T * Lq * R
    float U[3][3], Sv[3][3];
    #pragma unroll
    for (int i = 0; i < 3; i++)
        #pragma unroll
        for (int j = 0; j < 3; j++)
            U[i][j] = lq[i][0]*R[0][j] + lq[i][1]*R[1][j] + lq[i][2]*R[2][j];
    #pragma unroll
    for (int i = 0; i < 3; i++)
        #pragma unroll
        for (int j = 0; j < 3; j++)
            Sv[i][j] = R[0][i]*U[0][j] + R[1][i]*U[1][j] + R[2][i]*U[2][j];
    o = S + (size_t)t * 6;
    o[0]=Sv[0][0]; o[1]=Sv[0][1]; o[2]=Sv[0][2]; o[3]=Sv[1][1]; o[4]=Sv[1][2]; o[5]=Sv[2][2];
}

// ---------- kernel B (fused): one pass over beta ----------
// Block: 256 threads, RB=8 rows. Thread owns 4 consecutive cols per j-tile.
//   T[row]   = sum_j beta[row][j] * S[j]     (LDS transpose reduction)
//   partial[b][chunk][col] = sum_{r in block} beta[r][col]
__global__ __launch_bounds__(256) void fused_beta_kernel(
        const float* __restrict__ beta,
        const float* __restrict__ S,
        float* __restrict__ T,
        float* __restrict__ partial,  // B * (N/RB) * N
        int B, int N) {
    int tid = threadIdx.x;
    int grow0 = blockIdx.x * RB;         // global row start (B*N space)
    int b = grow0 / N;
    int chunksPerB = N / RB;
    int chunk = (grow0 - b * N) / RB;
    const float* sb = S + (size_t)b * N * 6;

    float acc[RB][6];
    #pragma unroll
    for (int r = 0; r < RB; r++)
        #pragma unroll
        for (int c = 0; c < 6; c++) acc[r][c] = 0.0f;

    int jtiles = N / 1024;               // 4 cols/thread * 256 threads
    for (int jt = 0; jt < jtiles; jt++) {
        int c0 = jt * 1024 + 4 * tid;
        float4 s4[6];
        const float4* sp = (const float4*)(sb + (size_t)c0 * 6);
        #pragma unroll
        for (int u = 0; u < 6; u++) s4[u] = sp[u];
        const float* sv = (const float*)s4;   // sv[u*6 + c] = S[c0+u][c]

        float csum0 = 0.f, csum1 = 0.f, csum2 = 0.f, csum3 = 0.f;
        #pragma unroll
        for (int r = 0; r < RB; r++) {
            float4 w4 = *(const float4*)(beta + (size_t)(grow0 + r) * N + c0);
            csum0 += w4.x; csum1 += w4.y; csum2 += w4.z; csum3 += w4.w;
            #pragma unroll
            for (int c = 0; c < 6; c++) {
                acc[r][c] += w4.x * sv[0*6 + c];
                acc[r][c] += w4.y * sv[1*6 + c];
                acc[r][c] += w4.z * sv[2*6 + c];
                acc[r][c] += w4.w * sv[3*6 + c];
            }
        }
        *(float4*)(partial + ((size_t)b * chunksPerB + chunk) * N + c0) =
            make_float4(csum0, csum1, csum2, csum3);
    }

    // ---- LDS transpose reduction: 256 threads x 48 values -> 48 sums ----
    __shared__ float red[256][49];   // stride 49: 2-way bank alias (free)
    __shared__ float red2[4][48];
    #pragma unroll
    for (int r = 0; r < RB; r++)
        #pragma unroll
        for (int c = 0; c < 6; c++)
            red[tid][r * 6 + c] = acc[r][c];
    __syncthreads();
    if (tid < 192) {
        int v = tid % 48, grp = tid / 48;   // 4 groups of 64 rows
        float s = 0.0f;
        #pragma unroll 8
        for (int r = 0; r < 64; r++) s += red[grp * 64 + r][v];
        red2[grp][v] = s;
    }
    __syncthreads();
    if (tid < 48) {
        float v = red2[0][tid] + red2[1][tid] + red2[2][tid] + red2[3][tid];
        T[(size_t)grow0 * 6 + tid] = v;    // 48 contiguous floats
    }
}

// ---------- kernel C: reduce partial chunks (N/RB) -> NCH2 ----------
__global__ void colsum_hop_kernel(const float* __restrict__ partial,
                                  float* __restrict__ partial2, // B*NCH2*N
                                  int B, int N) {
    int colTiles = N / 256;
    int idx = blockIdx.x;
    int ct  = idx % colTiles;
    int g   = (idx / colTiles) % NCH2;
    int b   = idx / (colTiles * NCH2);
    int col = ct * 256 + threadIdx.x;
    int chunksPerB = N / RB;
    int chg = chunksPerB / NCH2;           // 8
    const float* p = partial + ((size_t)b * chunksPerB + g * chg) * N + col;
    float s = 0.0f;
    #pragma unroll 8
    for (int k = 0; k < chg; k++) { s += *p; p += N; }
    partial2[((size_t)b * NCH2 + g) * N + col] = s;
}

// ---------- kernel D: finalize ----------
__global__ void finalize_kernel(const float* __restrict__ Lp,
                                const float* __restrict__ Lq,
                                const float* __restrict__ Rm,
                                const float* __restrict__ T,
                                const float* __restrict__ partial2,
                                float* __restrict__ out,
                                int B, int N) {
    int t = blockIdx.x * blockDim.x + threadIdx.x;
    int BN = B * N;
    if (t >= BN) return;
    int b = t / N;
    int i = t - b * N;

    float cs = 0.0f;
    #pragma unroll 8
    for (int c = 0; c < NCH2; c++)
        cs += partial2[((size_t)b * NCH2 + c) * N + i];

    const float* p = Rm + (size_t)t * 9;
    float R[3][3];
    #pragma unroll
    for (int ii = 0; ii < 3; ii++)
        #pragma unroll
        for (int jj = 0; jj < 3; jj++) R[ii][jj] = p[ii*3 + jj];

    const float* tp = T + (size_t)t * 6;
    float Tm[3][3] = {{tp[0],tp[1],tp[2]},{tp[1],tp[3],tp[4]},{tp[2],tp[4],tp[5]}};
    const float* lpp = Lp + (size_t)t * 6;
    const float* lqp = Lq + (size_t)t * 6;
    float Lpf[3][3] = {{lpp[0],lpp[1],lpp[2]},{lpp[1],lpp[3],lpp[4]},{lpp[2],lpp[4],lpp[5]}};
    float Lqf[3][3] = {{lqp[0],lqp[1],lqp[2]},{lqp[1],lqp[3],lqp[4]},{lqp[2],lqp[4],lqp[5]}};

    // M = Lp + R*Tm*R^T + cs*Lq
    float U[3][3], M[3][3];
    #pragma unroll
    for (int ii = 0; ii < 3; ii++)
        #pragma unroll
        for (int jj = 0; jj < 3; jj++)
            U[ii][jj] = R[ii][0]*Tm[0][jj] + R[ii][1]*Tm[1][jj] + R[ii][2]*Tm[2][jj];
    #pragma unroll
    for (int ii = 0; ii < 3; ii++)
        #pragma unroll
        for (int jj = 0; jj < 3; jj++) {
            float min_ij = U[ii][0]*R[jj][0] + U[ii][1]*R[jj][1] + U[ii][2]*R[jj][2];
            M[ii][jj] = Lpf[ii][jj] + min_ij + cs * Lqf[ii][jj];
        }
    // symmetrize
    float A[3][3];
    #pragma unroll
    for (int ii = 0; ii < 3; ii++)
        #pragma unroll
        for (int jj = 0; jj < 3; jj++) A[ii][jj] = 0.5f * (M[ii][jj] + M[jj][ii]);

    // Jacobi eigensolve, 6 sweeps
    float V[3][3] = {{1,0,0},{0,1,0},{0,0,1}};
    #pragma unroll
    for (int sweep = 0; sweep < 6; sweep++) {
        jrot(A, V, 0, 1);
        jrot(A, V, 0, 2);
        jrot(A, V, 1, 2);
    }
    float w0 = fmaxf(A[0][0], MIN_EIG_F);
    float w1 = fmaxf(A[1][1], MIN_EIG_F);
    float w2 = fmaxf(A[2][2], MIN_EIG_F);
    float iw0 = 1.0f/w0, iw1 = 1.0f/w1, iw2 = 1.0f/w2;

    float* opd = out + (size_t)t * 9;
    float* oin = out + (size_t)BN * 9 + (size_t)t * 9;
    #pragma unroll
    for (int ii = 0; ii < 3; ii++)
        #pragma unroll
        for (int jj = 0; jj < 3; jj++) {
            float pd = V[ii][0]*w0*V[jj][0] + V[ii][1]*w1*V[jj][1] + V[ii][2]*w2*V[jj][2];
            float iv = V[ii][0]*iw0*V[jj][0] + V[ii][1]*iw1*V[jj][1] + V[ii][2]*iw2*V[jj][2];
            opd[ii*3 + jj] = pd;
            oin[ii*3 + jj] = iv;
        }
}

extern "C" void kernel_launch(void* const* d_in, const int* in_sizes, int n_in,
                              void* d_out, int out_size, void* d_ws, size_t ws_size,
                              hipStream_t stream) {
    const float* Sp   = (const float*)d_in[0];
    const float* Sq   = (const float*)d_in[1];
    const float* phi  = (const float*)d_in[2];
    const float* beta = (const float*)d_in[3];

    int BN = in_sizes[2] / 3;                 // B*N
    int N  = (int)((long long)in_sizes[3] / BN);
    int B  = BN / N;

    float* ws = (float*)d_ws;
    float* Lp = ws;                   // BN*6
    float* Lq = Lp + (size_t)BN * 6;  // BN*6
    float* Rm = Lq + (size_t)BN * 6;  // BN*9
    float* S  = Rm + (size_t)BN * 9;  // BN*6
    float* T  = S  + (size_t)BN * 6;  // BN*6
    float* partial  = T + (size_t)BN * 6;            // B*(N/RB)*N
    float* partial2 = partial + (size_t)BN / RB * N; // B*NCH2*N

    float* outf = (float*)d_out;

    precompute_kernel<<<(BN + 63)/64, 64, 0, stream>>>(Sp, Sq, phi, Lp, Lq, Rm, S, BN);

    fused_beta_kernel<<<BN / RB, 256, 0, stream>>>(beta, S, T, partial, B, N);

    int colTiles = N / 256;
    colsum_hop_kernel<<<B * NCH2 * colTiles, 256, 0, stream>>>(partial, partial2, B, N);

    finalize_kernel<<<(BN + 63)/64, 64, 0, stream>>>(Lp, Lq, Rm, T, partial2, outf, B, N);
}